// Round 1
// baseline (445.839 us; speedup 1.0000x reference)
//
#include <hip/hip_runtime.h>

#define N_ROWS 262144
#define DIM 64
#define M_CONS 256
#define ROWS_PER_CHUNK 8
#define NCHUNK (N_ROWS / ROWS_PER_CHUNK)
#define ZT_PITCH 12   // pad so float4 reads at d*12 are 16B aligned, banks spread
#define AL_PITCH 10   // 2-way bank conflicts only (free on CDNA4), 8B aligned

__global__ __launch_bounds__(256, 4)
void fused_constrain_kernel(const float* __restrict__ z,
                            const float* __restrict__ pivot,
                            const float* __restrict__ At,
                            const float* __restrict__ b,
                            float* __restrict__ out) {
    __shared__ float lds_zt[DIM * ZT_PITCH];     // z tile, transposed [d][row]
    __shared__ float lds_al[M_CONS * AL_PITCH];  // masked alphas [m][row]

    const int tid = threadIdx.x;

    // ---- per-thread column-constant setup (once per block) ----
    float at[DIM];
#pragma unroll
    for (int d = 0; d < DIM; ++d) at[d] = At[d * M_CONS + tid];

    float c = 0.f;  // c[t] = pivot @ At[:,t]
#pragma unroll
    for (int d = 0; d < DIM; ++d) c = fmaf(pivot[d], at[d], c);

    const float bt = b[tid];

    const int srow = tid >> 5;          // 0..7 : row within chunk (staging/output)
    const int scol = (tid & 31) * 2;    // 0..62: d-pair (staging/output)
    const float2 p2 = *(const float2*)(pivot + scol);

    for (int chunk = blockIdx.x; chunk < NCHUNK; chunk += gridDim.x) {
        const int base = (chunk * ROWS_PER_CHUNK + srow) * DIM + scol;
        const float2 z2 = *(const float2*)(z + base);
        lds_zt[scol * ZT_PITCH + srow]       = z2.x;
        lds_zt[(scol + 1) * ZT_PITCH + srow] = z2.y;
        __syncthreads();

        // ---- s = z_rows @ At[:,tid] : 8 rows, broadcast z, At in regs ----
        float2 acc0 = {0.f, 0.f}, acc1 = {0.f, 0.f};
        float2 acc2 = {0.f, 0.f}, acc3 = {0.f, 0.f};
#pragma unroll
        for (int d = 0; d < DIM; ++d) {
            const float a = at[d];
            const float4 za = *(const float4*)&lds_zt[d * ZT_PITCH];
            const float4 zb = *(const float4*)&lds_zt[d * ZT_PITCH + 4];
            acc0.x = fmaf(za.x, a, acc0.x);
            acc0.y = fmaf(za.y, a, acc0.y);
            acc1.x = fmaf(za.z, a, acc1.x);
            acc1.y = fmaf(za.w, a, acc1.y);
            acc2.x = fmaf(zb.x, a, acc2.x);
            acc2.y = fmaf(zb.y, a, acc2.y);
            acc3.x = fmaf(zb.z, a, acc3.x);
            acc3.y = fmaf(zb.w, a, acc3.y);
        }

        // ---- epilogue: alpha = (s-b) / max(s-c, 1e-9), masked by (s-b)>=0 ----
        float s[8] = {acc0.x, acc0.y, acc1.x, acc1.y,
                      acc2.x, acc2.y, acc3.x, acc3.y};
#pragma unroll
        for (int j = 0; j < 8; ++j) {
            const float sa = s[j] - bt;
            const float nq = fmaxf(s[j] - c, 1e-9f);  // = -clamped_denom > 0
            const float alpha = sa * __builtin_amdgcn_rcpf(nq);
            s[j] = (sa >= 0.f) ? alpha : 0.f;         // masked alpha >= 0
        }

        {   // stage masked alphas: lds_al[m*10 + row]
            float* p = &lds_al[tid * AL_PITCH];
            *(float2*)(p)     = make_float2(s[0], s[1]);
            *(float2*)(p + 2) = make_float2(s[2], s[3]);
            *(float2*)(p + 4) = make_float2(s[4], s[5]);
            *(float2*)(p + 6) = make_float2(s[6], s[7]);
        }
        __syncthreads();

        // ---- row-max over 256 constraints: 8 strided reads + 32-lane butterfly
        const int t = tid & 31;
        float g = 0.f;
#pragma unroll
        for (int k = 0; k < 8; ++k)
            g = fmaxf(g, lds_al[(t + 32 * k) * AL_PITCH + srow]);
#pragma unroll
        for (int off = 1; off < 32; off <<= 1)
            g = fmaxf(g, __shfl_xor(g, off));

        // ---- out = z + g * (pivot - z), reusing staged z2 registers ----
        float2 o;
        o.x = fmaf(g, p2.x - z2.x, z2.x);
        o.y = fmaf(g, p2.y - z2.y, z2.y);
        *(float2*)(out + base) = o;
        // no extra barrier needed: next iter's zt writes are fenced by the
        // sync after staging; al(k+1) writes are fenced by that same barrier.
    }
}

extern "C" void kernel_launch(void* const* d_in, const int* in_sizes, int n_in,
                              void* d_out, int out_size, void* d_ws, size_t ws_size,
                              hipStream_t stream) {
    const float* z     = (const float*)d_in[0];
    const float* pivot = (const float*)d_in[1];
    const float* At    = (const float*)d_in[2];
    const float* b     = (const float*)d_in[3];
    fused_constrain_kernel<<<dim3(1024), dim3(256), 0, stream>>>(
        z, pivot, At, b, (float*)d_out);
}

// Round 2
// 362.477 us; speedup vs baseline: 1.2300x; 1.2300x over previous
//
#include <hip/hip_runtime.h>

#define DIMK 64
#define MC 256
#define RPT 16                      // rows per thread
#define RPB 128                     // rows per block (8 groups x 16)
#define NB 2048                     // 262144 / 128

__global__ __launch_bounds__(256, 3)
void fused_constrain_kernel(const float* __restrict__ z,
                            const float* __restrict__ pivot,
                            const float* __restrict__ At,
                            const float* __restrict__ b,
                            float* __restrict__ out) {
    __shared__ float lds_z[RPB * DIMK];   // 32 KB, row-major z tile

    const int tid  = threadIdx.x;
    const int m    = tid & 31;            // owns cols m*8 .. m*8+7
    const int g    = tid >> 5;            // owns rows g*16 .. g*16+15
    const int col0 = m * 8;
    const int row0 = g * RPT;
    const int base = blockIdx.x * (RPB * DIMK);

    // ---- stage 128x64 z tile into LDS (coalesced float4) ----
    {
        const float4* __restrict__ src = (const float4*)(z + base);
        float4* dst = (float4*)lds_z;
#pragma unroll
        for (int p = 0; p < 8; ++p)
            dst[p * 256 + tid] = src[p * 256 + tid];
    }
    __syncthreads();

    // ---- S = z_tile @ At : 16 rows x 8 cols per thread ----
    float acc[RPT][8];
#pragma unroll
    for (int r = 0; r < RPT; ++r)
#pragma unroll
        for (int c = 0; c < 8; ++c) acc[r][c] = 0.f;

#pragma unroll 2
    for (int k = 0; k < DIMK; ++k) {
        // At row slice from global (L1/L2-hot: At is 64 KB, reused by all blocks)
        const float4 a0 = *(const float4*)(At + k * MC + col0);
        const float4 a1 = *(const float4*)(At + k * MC + col0 + 4);
#pragma unroll
        for (int r = 0; r < RPT; ++r) {
            const float zv = lds_z[(row0 + r) * DIMK + k];  // broadcast read
            acc[r][0] = fmaf(zv, a0.x, acc[r][0]);
            acc[r][1] = fmaf(zv, a0.y, acc[r][1]);
            acc[r][2] = fmaf(zv, a0.z, acc[r][2]);
            acc[r][3] = fmaf(zv, a0.w, acc[r][3]);
            acc[r][4] = fmaf(zv, a1.x, acc[r][4]);
            acc[r][5] = fmaf(zv, a1.y, acc[r][5]);
            acc[r][6] = fmaf(zv, a1.z, acc[r][6]);
            acc[r][7] = fmaf(zv, a1.w, acc[r][7]);
        }
    }

    // ---- per-thread constants (post-loop: keeps k-loop register pressure low)
    float bv[8], cv[8];
    {
        const float4 b0 = *(const float4*)(b + col0);
        const float4 b1 = *(const float4*)(b + col0 + 4);
        bv[0] = b0.x; bv[1] = b0.y; bv[2] = b0.z; bv[3] = b0.w;
        bv[4] = b1.x; bv[5] = b1.y; bv[6] = b1.z; bv[7] = b1.w;
    }
#pragma unroll
    for (int c = 0; c < 8; ++c) cv[c] = 0.f;
    for (int k = 0; k < DIMK; ++k) {      // c = pivot @ At[:,col]
        const float pk = pivot[k];
        const float4 a0 = *(const float4*)(At + k * MC + col0);
        const float4 a1 = *(const float4*)(At + k * MC + col0 + 4);
        cv[0] = fmaf(pk, a0.x, cv[0]);
        cv[1] = fmaf(pk, a0.y, cv[1]);
        cv[2] = fmaf(pk, a0.z, cv[2]);
        cv[3] = fmaf(pk, a0.w, cv[3]);
        cv[4] = fmaf(pk, a1.x, cv[4]);
        cv[5] = fmaf(pk, a1.y, cv[5]);
        cv[6] = fmaf(pk, a1.z, cv[6]);
        cv[7] = fmaf(pk, a1.w, cv[7]);
    }
    const float2 p2 = *(const float2*)(pivot + 2 * m);

    // ---- epilogue: masked alpha, per-row max, rescale, store ----
#pragma unroll
    for (int r = 0; r < RPT; ++r) {
        float gm = 0.f;
#pragma unroll
        for (int c = 0; c < 8; ++c) {
            const float s  = acc[r][c];
            const float sa = s - bv[c];                       // sign_arg
            const float q  = fmaxf(s - cv[c], 1e-9f);         // -clamped denom
            const float al = sa * __builtin_amdgcn_rcpf(q);
            gm = fmaxf(gm, (sa >= 0.f) ? al : 0.f);
        }
        // reduce max over the 32 m-threads (within half-wave: off <= 16)
#pragma unroll
        for (int off = 1; off < 32; off <<= 1)
            gm = fmaxf(gm, __shfl_xor(gm, off));
        // out[row][2m..2m+1] = z + gm * (pivot - z)
        const int ro = (row0 + r) * DIMK;
        const float2 z2 = *(const float2*)&lds_z[ro + 2 * m];
        float2 o;
        o.x = fmaf(gm, p2.x - z2.x, z2.x);
        o.y = fmaf(gm, p2.y - z2.y, z2.y);
        *(float2*)(out + base + ro + 2 * m) = o;
    }
}

extern "C" void kernel_launch(void* const* d_in, const int* in_sizes, int n_in,
                              void* d_out, int out_size, void* d_ws, size_t ws_size,
                              hipStream_t stream) {
    const float* z     = (const float*)d_in[0];
    const float* pivot = (const float*)d_in[1];
    const float* At    = (const float*)d_in[2];
    const float* b     = (const float*)d_in[3];
    fused_constrain_kernel<<<dim3(NB), dim3(256), 0, stream>>>(
        z, pivot, At, b, (float*)d_out);
}

// Round 3
// 276.372 us; speedup vs baseline: 1.6132x; 1.3116x over previous
//
#include <hip/hip_runtime.h>

typedef float v2f __attribute__((ext_vector_type(2)));

#define DIMK 64
#define MC 256
#define RPT 8                 // rows per thread
#define RPB 64                // rows per block (8 groups x 8)
#define NB (262144 / RPB)     // 4096 blocks

// tiny pre-kernel: cvec[t] = pivot @ At[:,t]
__global__ void precompute_c(const float* __restrict__ pivot,
                             const float* __restrict__ At,
                             float* __restrict__ cvec) {
    const int t = threadIdx.x;
    float acc = 0.f;
    for (int k = 0; k < DIMK; ++k) acc = fmaf(pivot[k], At[k * MC + t], acc);
    cvec[t] = acc;
}

__global__ __launch_bounds__(256, 4)
void fused_constrain_kernel(const float* __restrict__ z,
                            const float* __restrict__ pivot,
                            const float* __restrict__ At,
                            const float* __restrict__ b,
                            const float* __restrict__ cvec,
                            float* __restrict__ out) {
    __shared__ float lds_z[RPB * DIMK];   // 16 KB z tile

    const int tid  = threadIdx.x;
    const int m    = tid & 31;            // owns cols m*8 .. m*8+7
    const int g    = tid >> 5;            // owns rows g*8 .. g*8+7
    const int row0 = g * RPT;
    const int col0 = m * 8;
    const int base = blockIdx.x * (RPB * DIMK);

    // ---- stage 64x64 z tile (coalesced float4, 4 per thread) ----
    {
        const float4* __restrict__ src = (const float4*)(z + base);
        float4* dst = (float4*)lds_z;
#pragma unroll
        for (int p = 0; p < 4; ++p)
            dst[p * 256 + tid] = src[p * 256 + tid];
    }
    __syncthreads();

    // ---- S = z_tile @ At : 8 rows x 8 cols per thread, packed-f32 accs ----
    v2f acc[RPT][4];
#pragma unroll
    for (int r = 0; r < RPT; ++r)
#pragma unroll
        for (int c = 0; c < 4; ++c) acc[r][c] = (v2f){0.f, 0.f};

    const float4* __restrict__ At4 = (const float4*)At;   // row k at [k*64 + m*2]
    float4 a0 = At4[m * 2];
    float4 a1 = At4[m * 2 + 1];

#pragma unroll 2
    for (int kb = 0; kb < DIMK / 4; ++kb) {
        float4 z4[RPT];                    // 4 k-steps of this thread's 8 rows
#pragma unroll
        for (int r = 0; r < RPT; ++r)
            z4[r] = *(const float4*)&lds_z[(row0 + r) * DIMK + kb * 4];
#pragma unroll
        for (int kk = 0; kk < 4; ++kk) {
            const int kn = (kb * 4 + kk + 1) & (DIMK - 1);  // wrap: last prefetch re-reads row0, harmless
            const float4 n0 = At4[kn * 64 + m * 2];
            const float4 n1 = At4[kn * 64 + m * 2 + 1];
            const v2f a[4] = {{a0.x, a0.y}, {a0.z, a0.w}, {a1.x, a1.y}, {a1.z, a1.w}};
#pragma unroll
            for (int r = 0; r < RPT; ++r) {
                const float zs = (kk == 0) ? z4[r].x : (kk == 1) ? z4[r].y
                               : (kk == 2) ? z4[r].z : z4[r].w;
                const v2f zz = {zs, zs};
                acc[r][0] = __builtin_elementwise_fma(zz, a[0], acc[r][0]);
                acc[r][1] = __builtin_elementwise_fma(zz, a[1], acc[r][1]);
                acc[r][2] = __builtin_elementwise_fma(zz, a[2], acc[r][2]);
                acc[r][3] = __builtin_elementwise_fma(zz, a[3], acc[r][3]);
            }
            a0 = n0; a1 = n1;
        }
    }

    // ---- per-thread constants (post-loop) ----
    float bv[8], cv[8];
    {
        const float4 b0 = *(const float4*)(b + col0);
        const float4 b1 = *(const float4*)(b + col0 + 4);
        bv[0] = b0.x; bv[1] = b0.y; bv[2] = b0.z; bv[3] = b0.w;
        bv[4] = b1.x; bv[5] = b1.y; bv[6] = b1.z; bv[7] = b1.w;
        const float4 c0 = *(const float4*)(cvec + col0);
        const float4 c1 = *(const float4*)(cvec + col0 + 4);
        cv[0] = c0.x; cv[1] = c0.y; cv[2] = c0.z; cv[3] = c0.w;
        cv[4] = c1.x; cv[5] = c1.y; cv[6] = c1.z; cv[7] = c1.w;
    }
    const float2 p2 = *(const float2*)(pivot + 2 * m);

    // ---- epilogue: masked alpha, row-max over 32 m-lanes, rescale, store ----
#pragma unroll
    for (int r = 0; r < RPT; ++r) {
        float gm = 0.f;
#pragma unroll
        for (int c = 0; c < 4; ++c) {
#pragma unroll
            for (int j = 0; j < 2; ++j) {
                const float s  = acc[r][c][j];
                const float sa = s - bv[2 * c + j];
                const float q  = fmaxf(s - cv[2 * c + j], 1e-9f);
                const float al = sa * __builtin_amdgcn_rcpf(q);
                gm = fmaxf(gm, (sa >= 0.f) ? al : 0.f);
            }
        }
#pragma unroll
        for (int off = 1; off < 32; off <<= 1)   // stays within 32-lane half
            gm = fmaxf(gm, __shfl_xor(gm, off));
        const int ro = (row0 + r) * DIMK + 2 * m;
        const float2 z2 = *(const float2*)&lds_z[ro];
        float2 o;
        o.x = fmaf(gm, p2.x - z2.x, z2.x);
        o.y = fmaf(gm, p2.y - z2.y, z2.y);
        *(float2*)(out + base + ro) = o;
    }
}

extern "C" void kernel_launch(void* const* d_in, const int* in_sizes, int n_in,
                              void* d_out, int out_size, void* d_ws, size_t ws_size,
                              hipStream_t stream) {
    const float* z     = (const float*)d_in[0];
    const float* pivot = (const float*)d_in[1];
    const float* At    = (const float*)d_in[2];
    const float* b     = (const float*)d_in[3];
    float* cvec = (float*)d_ws;                      // 256 floats of scratch
    precompute_c<<<dim3(1), dim3(MC), 0, stream>>>(pivot, At, cvec);
    fused_constrain_kernel<<<dim3(NB), dim3(256), 0, stream>>>(
        z, pivot, At, b, cvec, (float*)d_out);
}

// Round 4
// 210.077 us; speedup vs baseline: 2.1223x; 1.3156x over previous
//
#include <hip/hip_runtime.h>

typedef float v2f __attribute__((ext_vector_type(2)));

#define DIMK 64
#define MC 256
#define RPT 8                 // rows per thread
#define RPB 64                // rows per block (8 groups x 8)
#define NB (262144 / RPB)     // 4096 blocks

// tiny pre-kernel: cvec[t] = pivot @ At[:,t]
__global__ void precompute_c(const float* __restrict__ pivot,
                             const float* __restrict__ At,
                             float* __restrict__ cvec) {
    const int t = threadIdx.x;
    float acc = 0.f;
    for (int k = 0; k < DIMK; ++k) acc = fmaf(pivot[k], At[k * MC + t], acc);
    cvec[t] = acc;
}

__global__ __launch_bounds__(256) __attribute__((amdgpu_waves_per_eu(4, 4)))
void fused_constrain_kernel(const float* __restrict__ z,
                            const float* __restrict__ pivot,
                            const float* __restrict__ At,
                            const float* __restrict__ b,
                            const float* __restrict__ cvec,
                            float* __restrict__ out) {
    __shared__ float lds_z[RPB * DIMK];   // 16 KB z tile

    const int tid  = threadIdx.x;
    const int m    = tid & 31;            // owns cols m*8 .. m*8+7
    const int g    = tid >> 5;            // owns rows g*8 .. g*8+7
    const int row0 = g * RPT;
    const int col0 = m * 8;
    const int base = blockIdx.x * (RPB * DIMK);

    // ---- stage 64x64 z tile (coalesced float4, 4 per thread) ----
    {
        const float4* __restrict__ src = (const float4*)(z + base);
        float4* dst = (float4*)lds_z;
#pragma unroll
        for (int p = 0; p < 4; ++p)
            dst[p * 256 + tid] = src[p * 256 + tid];
    }
    __syncthreads();

    // ---- S = z_tile @ At : 8 rows x 8 cols per thread, packed-f32 accs ----
    v2f acc[RPT][4];
#pragma unroll
    for (int r = 0; r < RPT; ++r)
#pragma unroll
        for (int c = 0; c < 4; ++c) acc[r][c] = (v2f){0.f, 0.f};

    const float4* __restrict__ At4 = (const float4*)At;   // row k: [k*64 + m*2]
    const int a_off = m * 2;

    for (int kb = 0; kb < DIMK / 2; ++kb) {               // 2 k-steps per iter
        float2 z2[RPT];                                   // b64 broadcast reads
#pragma unroll
        for (int r = 0; r < RPT; ++r)
            z2[r] = *(const float2*)&lds_z[(row0 + r) * DIMK + kb * 2];

        const float4 a0 = At4[(2 * kb) * 64 + a_off];
        const float4 a1 = At4[(2 * kb) * 64 + a_off + 1];
        const float4 a2 = At4[(2 * kb + 1) * 64 + a_off];
        const float4 a3 = At4[(2 * kb + 1) * 64 + a_off + 1];
        const v2f A0 = {a0.x, a0.y}, A1 = {a0.z, a0.w};
        const v2f A2 = {a1.x, a1.y}, A3 = {a1.z, a1.w};
        const v2f B0 = {a2.x, a2.y}, B1 = {a2.z, a2.w};
        const v2f B2 = {a3.x, a3.y}, B3 = {a3.z, a3.w};

#pragma unroll
        for (int r = 0; r < RPT; ++r) {
            const v2f zx = {z2[r].x, z2[r].x};
            acc[r][0] = __builtin_elementwise_fma(zx, A0, acc[r][0]);
            acc[r][1] = __builtin_elementwise_fma(zx, A1, acc[r][1]);
            acc[r][2] = __builtin_elementwise_fma(zx, A2, acc[r][2]);
            acc[r][3] = __builtin_elementwise_fma(zx, A3, acc[r][3]);
            const v2f zy = {z2[r].y, z2[r].y};
            acc[r][0] = __builtin_elementwise_fma(zy, B0, acc[r][0]);
            acc[r][1] = __builtin_elementwise_fma(zy, B1, acc[r][1]);
            acc[r][2] = __builtin_elementwise_fma(zy, B2, acc[r][2]);
            acc[r][3] = __builtin_elementwise_fma(zy, B3, acc[r][3]);
        }
    }

    // ---- per-thread constants (post-loop) ----
    float bv[8], cv[8];
    {
        const float4 b0 = *(const float4*)(b + col0);
        const float4 b1 = *(const float4*)(b + col0 + 4);
        bv[0] = b0.x; bv[1] = b0.y; bv[2] = b0.z; bv[3] = b0.w;
        bv[4] = b1.x; bv[5] = b1.y; bv[6] = b1.z; bv[7] = b1.w;
        const float4 c0 = *(const float4*)(cvec + col0);
        const float4 c1 = *(const float4*)(cvec + col0 + 4);
        cv[0] = c0.x; cv[1] = c0.y; cv[2] = c0.z; cv[3] = c0.w;
        cv[4] = c1.x; cv[5] = c1.y; cv[6] = c1.z; cv[7] = c1.w;
    }
    const float2 p2 = *(const float2*)(pivot + 2 * m);

    // ---- epilogue: masked alpha, row-max over 32 m-lanes, rescale, store ----
#pragma unroll
    for (int r = 0; r < RPT; ++r) {
        float gm = 0.f;
#pragma unroll
        for (int c = 0; c < 4; ++c) {
#pragma unroll
            for (int j = 0; j < 2; ++j) {
                const float s  = acc[r][c][j];
                const float sa = s - bv[2 * c + j];
                const float q  = fmaxf(s - cv[2 * c + j], 1e-9f);
                const float al = sa * __builtin_amdgcn_rcpf(q);
                gm = fmaxf(gm, (sa >= 0.f) ? al : 0.f);
            }
        }
#pragma unroll
        for (int off = 1; off < 32; off <<= 1)   // stays within 32-lane half
            gm = fmaxf(gm, __shfl_xor(gm, off));
        const int ro = (row0 + r) * DIMK + 2 * m;
        const float2 z2 = *(const float2*)&lds_z[ro];
        float2 o;
        o.x = fmaf(gm, p2.x - z2.x, z2.x);
        o.y = fmaf(gm, p2.y - z2.y, z2.y);
        *(float2*)(out + base + ro) = o;
    }
}

extern "C" void kernel_launch(void* const* d_in, const int* in_sizes, int n_in,
                              void* d_out, int out_size, void* d_ws, size_t ws_size,
                              hipStream_t stream) {
    const float* z     = (const float*)d_in[0];
    const float* pivot = (const float*)d_in[1];
    const float* At    = (const float*)d_in[2];
    const float* b     = (const float*)d_in[3];
    float* cvec = (float*)d_ws;                      // 256 floats of scratch
    precompute_c<<<dim3(1), dim3(MC), 0, stream>>>(pivot, At, cvec);
    fused_constrain_kernel<<<dim3(NB), dim3(256), 0, stream>>>(
        z, pivot, At, b, cvec, (float*)d_out);
}